// Round 10
// baseline (638.548 us; speedup 1.0000x reference)
//
#include <hip/hip_runtime.h>

#define NN 262144   // nodes
#define NE 1048576  // edges
#define NG 8192     // graphs
#define FD 64       // feature dim
#define AD 8        // adduct dim
#define DN 512      // dense dim

__device__ __forceinline__ int lowerBound(const int* __restrict__ a, int n, int v) {
  int lo = 0, hi = n;
  while (lo < hi) { int mid = (lo + hi) >> 1; if (a[mid] < v) lo = mid + 1; else hi = mid; }
  return lo;
}

// ---------------- CSR build ----------------
__global__ void k_count(const int* __restrict__ dst, int* __restrict__ counts) {
  int e = blockIdx.x * 256 + threadIdx.x;
  if (e < NE) atomicAdd(&counts[dst[e]], 1);
}

__global__ void k_scan1(const int* __restrict__ counts, int* __restrict__ rp,
                        int* __restrict__ bsum) {
  __shared__ int s[256];
  int tid = threadIdx.x;
  int i = blockIdx.x * 256 + tid;
  int orig = counts[i];
  s[tid] = orig;
  __syncthreads();
  for (int off = 1; off < 256; off <<= 1) {
    int v = (tid >= off) ? s[tid - off] : 0;
    __syncthreads();
    s[tid] += v;
    __syncthreads();
  }
  rp[i] = s[tid] - orig;  // block-local exclusive scan
  if (tid == 255) bsum[blockIdx.x] = s[tid];
}

__global__ void k_scan2(int* __restrict__ bsum) {
  __shared__ int s[1024];
  int tid = threadIdx.x;
  int orig = bsum[tid];
  s[tid] = orig;
  __syncthreads();
  for (int off = 1; off < 1024; off <<= 1) {
    int v = (tid >= off) ? s[tid - off] : 0;
    __syncthreads();
    s[tid] += v;
    __syncthreads();
  }
  bsum[tid] = s[tid] - orig;  // exclusive
}

__global__ void k_scan3(const int* __restrict__ counts, int* __restrict__ rp,
                        const int* __restrict__ bsum, int* __restrict__ cursor,
                        float* __restrict__ inv_deg) {
  int i = blockIdx.x * 256 + threadIdx.x;
  int v = rp[i] + bsum[blockIdx.x];
  rp[i] = v;
  cursor[i] = v;
  inv_deg[i] = 1.0f / (float)(counts[i] + 1);
  if (i == 0) rp[NN] = NE;
}

// R9: k_fill's 107 MB WRITE was amplification from two scattered 4B stores
// per edge (each dirties a random 64B line). Pack (src, norm) into ONE int2
// scatter -> dirty lines halve; aggregate's index loads halve too.
__global__ void k_fill(const int* __restrict__ src, const int* __restrict__ dst,
                       const int* __restrict__ counts, int* __restrict__ cursor,
                       int2* __restrict__ csr_se) {
  int e = blockIdx.x * 256 + threadIdx.x;
  int s = src[e], d = dst[e];
  float ds = (float)(counts[s] + 1);
  float dd = (float)(counts[d] + 1);
  int pos = atomicAdd(&cursor[d], 1);
  csr_se[pos] = make_int2(s, __float_as_int(rsqrtf(ds * dd)));
}

// ---------------- GCN: t = h @ W + b ----------------
// Classic LDS-tiled GEMM (validated R4: ~28 us/layer, no scratch traffic).
#define HS 68  // hsT row stride (floats): 68*4=272 B, 16B-aligned, breaks pow2 banks
__global__ void __launch_bounds__(256) k_transform(const float* __restrict__ hin,
                                                   const float* __restrict__ W,
                                                   const float* __restrict__ b,
                                                   float* __restrict__ tout) {
  __shared__ float hsT[64 * HS];  // [k][n]  17.4 KB
  __shared__ float Ws[64 * 64];   // [k][c]  16 KB
  int tid = threadIdx.x;
  size_t base = (size_t)blockIdx.x * 64 * 64;

  const float4* h4 = (const float4*)(hin + base);
#pragma unroll
  for (int j = 0; j < 4; j++) {
    int f = tid + 256 * j;        // float4 index within 64x64 tile
    int n = f >> 4, kq = f & 15;  // node row, k-quad
    float4 v = h4[f];
    hsT[(4 * kq + 0) * HS + n] = v.x;
    hsT[(4 * kq + 1) * HS + n] = v.y;
    hsT[(4 * kq + 2) * HS + n] = v.z;
    hsT[(4 * kq + 3) * HS + n] = v.w;
  }
  const float4* w4 = (const float4*)W;
  float4* ws4 = (float4*)Ws;
#pragma unroll
  for (int j = 0; j < 4; j++) ws4[tid + 256 * j] = w4[tid + 256 * j];
  __syncthreads();

  int n0 = (tid >> 4) * 4;  // node quad (16-lane broadcast, free)
  int c0 = (tid & 15) * 4;  // col quad (contiguous 256B, free)
  float acc[4][4];
#pragma unroll
  for (int i = 0; i < 4; i++)
#pragma unroll
    for (int j = 0; j < 4; j++) acc[i][j] = b[c0 + j];

#pragma unroll 4
  for (int k = 0; k < 64; k++) {
    float4 av = *(const float4*)&hsT[k * HS + n0];  // ds_read_b128
    float4 bv = *(const float4*)&Ws[k * 64 + c0];   // ds_read_b128
    acc[0][0] = fmaf(av.x, bv.x, acc[0][0]);
    acc[0][1] = fmaf(av.x, bv.y, acc[0][1]);
    acc[0][2] = fmaf(av.x, bv.z, acc[0][2]);
    acc[0][3] = fmaf(av.x, bv.w, acc[0][3]);
    acc[1][0] = fmaf(av.y, bv.x, acc[1][0]);
    acc[1][1] = fmaf(av.y, bv.y, acc[1][1]);
    acc[1][2] = fmaf(av.y, bv.z, acc[1][2]);
    acc[1][3] = fmaf(av.y, bv.w, acc[1][3]);
    acc[2][0] = fmaf(av.z, bv.x, acc[2][0]);
    acc[2][1] = fmaf(av.z, bv.y, acc[2][1]);
    acc[2][2] = fmaf(av.z, bv.z, acc[2][2]);
    acc[2][3] = fmaf(av.z, bv.w, acc[2][3]);
    acc[3][0] = fmaf(av.w, bv.x, acc[3][0]);
    acc[3][1] = fmaf(av.w, bv.y, acc[3][1]);
    acc[3][2] = fmaf(av.w, bv.z, acc[3][2]);
    acc[3][3] = fmaf(av.w, bv.w, acc[3][3]);
  }

  float4* o4 = (float4*)(tout + base);
#pragma unroll
  for (int i = 0; i < 4; i++) {
    o4[((n0 + i) * 64 + c0) >> 2] =
        make_float4(acc[i][0], acc[i][1], acc[i][2], acc[i][3]);
  }
}

// ---------------- Aggregate: h = relu(sum_{e->n} norm*t[src] + t[n]/deg) ----------------
// 16 lanes per row (float4/lane), 4 nodes/wave, unroll-2 streams (validated R9).
// Now reads packed int2 CSR entries (one 8B load per edge).
__global__ void k_aggregate(const float* __restrict__ t, const int* __restrict__ rp,
                            const int2* __restrict__ csr_se,
                            const float* __restrict__ inv_deg, float* __restrict__ hout) {
  int tid = threadIdx.x;
  int grp = tid >> 4;   // 16 node-groups per 256-thread block
  int ln  = tid & 15;   // feature quad within row
  int n = blockIdx.x * 16 + grp;
  int beg = rp[n], end = rp[n + 1];
  const float4* t4 = (const float4*)t;

  float4 v = t4[(size_t)n * 16 + ln];
  float sdeg = inv_deg[n];
  float4 a0 = make_float4(v.x * sdeg, v.y * sdeg, v.z * sdeg, v.w * sdeg);
  float4 a1 = make_float4(0.f, 0.f, 0.f, 0.f);

  int idx = beg;
  for (; idx + 2 <= end; idx += 2) {
    int2 e0 = csr_se[idx + 0];
    int2 e1 = csr_se[idx + 1];
    float w0 = __int_as_float(e0.y);
    float w1 = __int_as_float(e1.y);
    float4 v0 = t4[(size_t)e0.x * 16 + ln];
    float4 v1 = t4[(size_t)e1.x * 16 + ln];
    a0.x = fmaf(w0, v0.x, a0.x);
    a0.y = fmaf(w0, v0.y, a0.y);
    a0.z = fmaf(w0, v0.z, a0.z);
    a0.w = fmaf(w0, v0.w, a0.w);
    a1.x = fmaf(w1, v1.x, a1.x);
    a1.y = fmaf(w1, v1.y, a1.y);
    a1.z = fmaf(w1, v1.z, a1.z);
    a1.w = fmaf(w1, v1.w, a1.w);
  }
  if (idx < end) {
    int2 e0 = csr_se[idx];
    float w = __int_as_float(e0.y);
    float4 v0 = t4[(size_t)e0.x * 16 + ln];
    a0.x = fmaf(w, v0.x, a0.x);
    a0.y = fmaf(w, v0.y, a0.y);
    a0.z = fmaf(w, v0.z, a0.z);
    a0.w = fmaf(w, v0.w, a0.w);
  }
  float4 r;
  r.x = fmaxf(a0.x + a1.x, 0.f);
  r.y = fmaxf(a0.y + a1.y, 0.f);
  r.z = fmaxf(a0.z + a1.z, 0.f);
  r.w = fmaxf(a0.w + a1.w, 0.f);
  ((float4*)hout)[(size_t)n * 16 + ln] = r;
}

// ---------------- Readout: graph_ids sorted -> binary-search ranges ----------------
__global__ void k_readout(const float* __restrict__ h, const int* __restrict__ gids,
                          float* __restrict__ r) {
  int tid = threadIdx.x;
  int grp = tid >> 4, ln = tid & 15;
  int g = blockIdx.x * 16 + grp;
  int lo = lowerBound(gids, NN, g);
  int hi = lowerBound(gids, NN, g + 1);
  const float4* h4 = (const float4*)h;
  float4 a0 = make_float4(0.f, 0.f, 0.f, 0.f);
  float4 a1 = make_float4(0.f, 0.f, 0.f, 0.f);
  int n = lo;
  for (; n + 2 <= hi; n += 2) {
    float4 v0 = h4[(size_t)n * 16 + ln];
    float4 v1 = h4[(size_t)(n + 1) * 16 + ln];
    a0.x += v0.x; a0.y += v0.y; a0.z += v0.z; a0.w += v0.w;
    a1.x += v1.x; a1.y += v1.y; a1.z += v1.z; a1.w += v1.w;
  }
  if (n < hi) {
    float4 v0 = h4[(size_t)n * 16 + ln];
    a0.x += v0.x; a0.y += v0.y; a0.z += v0.z; a0.w += v0.w;
  }
  ((float4*)r)[(size_t)g * 16 + ln] =
      make_float4(a0.x + a1.x, a0.y + a1.y, a0.z + a1.z, a0.w + a1.w);
}

// ---------------- Dense head ----------------
// y1T[j][g] = relu(b1[j] + sum_k concat(r,xa)[g][k] * W1[k][j])
// TRANSPOSED output (g-contiguous rows) so dense2/out use lane=graph coalesced.
__global__ void __launch_bounds__(256) k_dense1(const float* __restrict__ r,
                                                const float* __restrict__ xa,
                                                const float* __restrict__ W1,
                                                const float* __restrict__ b1,
                                                float* __restrict__ y1T) {
  __shared__ float xs[8 * 72];
  int tid = threadIdx.x;
  int g0 = blockIdx.x * 8;
  for (int i = tid; i < 8 * 72; i += 256) {
    int g = i / 72, k = i % 72;
    xs[i] = (k < 64) ? r[(size_t)(g0 + g) * 64 + k] : xa[(size_t)(g0 + g) * 8 + (k - 64)];
  }
  __syncthreads();
  float acc[8][2];
#pragma unroll
  for (int g = 0; g < 8; g++) { acc[g][0] = 0.f; acc[g][1] = 0.f; }
  for (int k = 0; k < 72; k++) {
    float w0 = W1[k * 512 + tid];
    float w1 = W1[k * 512 + 256 + tid];
#pragma unroll
    for (int g = 0; g < 8; g++) {
      float xv = xs[g * 72 + k];  // wave-uniform broadcast
      acc[g][0] = fmaf(xv, w0, acc[g][0]);
      acc[g][1] = fmaf(xv, w1, acc[g][1]);
    }
  }
  float bb0 = b1[tid], bb1 = b1[256 + tid];
  float4 v;
  v = make_float4(fmaxf(acc[0][0] + bb0, 0.f), fmaxf(acc[1][0] + bb0, 0.f),
                  fmaxf(acc[2][0] + bb0, 0.f), fmaxf(acc[3][0] + bb0, 0.f));
  *(float4*)&y1T[(size_t)tid * NG + g0] = v;
  v = make_float4(fmaxf(acc[4][0] + bb0, 0.f), fmaxf(acc[5][0] + bb0, 0.f),
                  fmaxf(acc[6][0] + bb0, 0.f), fmaxf(acc[7][0] + bb0, 0.f));
  *(float4*)&y1T[(size_t)tid * NG + g0 + 4] = v;
  v = make_float4(fmaxf(acc[0][1] + bb1, 0.f), fmaxf(acc[1][1] + bb1, 0.f),
                  fmaxf(acc[2][1] + bb1, 0.f), fmaxf(acc[3][1] + bb1, 0.f));
  *(float4*)&y1T[(size_t)(256 + tid) * NG + g0] = v;
  v = make_float4(fmaxf(acc[4][1] + bb1, 0.f), fmaxf(acc[5][1] + bb1, 0.f),
                  fmaxf(acc[6][1] + bb1, 0.f), fmaxf(acc[7][1] + bb1, 0.f));
  *(float4*)&y1T[(size_t)(256 + tid) * NG + g0 + 4] = v;
}

// y2T = relu(W2^T @ y1T + b2). R7/R8 both plateaued at ~6.3 TB/s of L2/L3
// xT re-reads (32 j-blocks x 16 MB = 512 MB) -- BW-bound, not latency (2x TLP
// changed nothing). Fix: j-slice 32 (W2 slice 64 KB LDS) -> 16 j-blocks ->
// 256 MB traffic. 2 graphs/thread keeps fma:ds_read at 8:1 (8 broadcast b128
// + 64 fma per k). 256 blocks; 8-deep x prefetch covers L3 latency.
__global__ void __launch_bounds__(256) k_dense2(const float* __restrict__ xT,
                                                const float* __restrict__ W2,
                                                const float* __restrict__ b2,
                                                float* __restrict__ y2T) {
  __shared__ float ws[512 * 32];  // [k][j-slice 32]  64 KB
  int tid = threadIdx.x;
  int gA = (blockIdx.x & 15) * 512 + tid;  // graphs [gb*512 .. gb*512+512)
  int gB = gA + 256;
  int j0 = (blockIdx.x >> 4) * 32;
  {
    int u = tid & 31, kb = tid >> 3 >> 2;  // 8 k-rows per sweep
#pragma unroll
    for (int i = 0; i < 64; i++) {
      int k = kb + 8 * i;
      ws[k * 32 + u] = W2[(size_t)k * 512 + j0 + u];  // 128B segs, coalesced
    }
  }
  float accA[32], accB[32];
#pragma unroll
  for (int u = 0; u < 32; u++) { float bb = b2[j0 + u]; accA[u] = bb; accB[u] = bb; }
  __syncthreads();

  float pa0 = xT[gA];
  float pa1 = xT[(size_t)1 * NG + gA];
  float pa2 = xT[(size_t)2 * NG + gA];
  float pa3 = xT[(size_t)3 * NG + gA];
  float pb0 = xT[gB];
  float pb1 = xT[(size_t)1 * NG + gB];
  float pb2 = xT[(size_t)2 * NG + gB];
  float pb3 = xT[(size_t)3 * NG + gB];
#pragma unroll 1
  for (int k = 0; k < 512; k += 4) {
    float a0 = pa0, a1 = pa1, a2 = pa2, a3 = pa3;
    float b0 = pb0, b1 = pb1, b2v = pb2, b3 = pb3;
    if (k + 4 < 512) {
      pa0 = xT[(size_t)(k + 4) * NG + gA];
      pa1 = xT[(size_t)(k + 5) * NG + gA];
      pa2 = xT[(size_t)(k + 6) * NG + gA];
      pa3 = xT[(size_t)(k + 7) * NG + gA];
      pb0 = xT[(size_t)(k + 4) * NG + gB];
      pb1 = xT[(size_t)(k + 5) * NG + gB];
      pb2 = xT[(size_t)(k + 6) * NG + gB];
      pb3 = xT[(size_t)(k + 7) * NG + gB];
    }
#pragma unroll
    for (int kk = 0; kk < 4; kk++) {
      float pA = (kk == 0) ? a0 : (kk == 1) ? a1 : (kk == 2) ? a2 : a3;
      float pB = (kk == 0) ? b0 : (kk == 1) ? b1 : (kk == 2) ? b2v : b3;
#pragma unroll
      for (int q = 0; q < 8; q++) {
        const float4 w = *(const float4*)&ws[(k + kk) * 32 + 4 * q];  // broadcast b128
        accA[4 * q + 0] = fmaf(pA, w.x, accA[4 * q + 0]);
        accA[4 * q + 1] = fmaf(pA, w.y, accA[4 * q + 1]);
        accA[4 * q + 2] = fmaf(pA, w.z, accA[4 * q + 2]);
        accA[4 * q + 3] = fmaf(pA, w.w, accA[4 * q + 3]);
        accB[4 * q + 0] = fmaf(pB, w.x, accB[4 * q + 0]);
        accB[4 * q + 1] = fmaf(pB, w.y, accB[4 * q + 1]);
        accB[4 * q + 2] = fmaf(pB, w.z, accB[4 * q + 2]);
        accB[4 * q + 3] = fmaf(pB, w.w, accB[4 * q + 3]);
      }
    }
  }
#pragma unroll
  for (int u = 0; u < 32; u++) {
    y2T[(size_t)(j0 + u) * NG + gA] = fmaxf(accA[u], 0.f);
    y2T[(size_t)(j0 + u) * NG + gB] = fmaxf(accB[u], 0.f);
  }
}

// out[g] = y2T[:,g] . out_W + out_b  -- lane = graph, coalesced, no shuffle
__global__ void k_out(const float* __restrict__ y2T, const float* __restrict__ ow,
                      const float* __restrict__ ob, float* __restrict__ out) {
  int g = blockIdx.x * 256 + threadIdx.x;
  float s0 = 0.f, s1 = 0.f, s2 = 0.f, s3 = 0.f;
#pragma unroll 4
  for (int j = 0; j < 512; j += 4) {
    s0 = fmaf(y2T[(size_t)(j + 0) * NG + g], ow[j + 0], s0);
    s1 = fmaf(y2T[(size_t)(j + 1) * NG + g], ow[j + 1], s1);
    s2 = fmaf(y2T[(size_t)(j + 2) * NG + g], ow[j + 2], s2);
    s3 = fmaf(y2T[(size_t)(j + 3) * NG + g], ow[j + 3], s3);
  }
  out[g] = (s0 + s1) + (s2 + s3) + ob[0];
}

extern "C" void kernel_launch(void* const* d_in, const int* in_sizes, int n_in,
                              void* d_out, int out_size, void* d_ws, size_t ws_size,
                              hipStream_t stream) {
  const float* x_mol    = (const float*)d_in[0];
  const float* x_adduct = (const float*)d_in[1];
  const int*   edge_src = (const int*)d_in[2];
  const int*   edge_dst = (const int*)d_in[3];
  const int*   graph_ids= (const int*)d_in[4];
  const float* gcn_W    = (const float*)d_in[5];
  const float* gcn_b    = (const float*)d_in[6];
  const float* d1W      = (const float*)d_in[7];
  const float* d1b      = (const float*)d_in[8];
  const float* d2W      = (const float*)d_in[9];
  const float* d2b      = (const float*)d_in[10];
  const float* oW       = (const float*)d_in[11];
  const float* obias    = (const float*)d_in[12];
  float* out = (float*)d_out;

  char* p = (char*)d_ws;
  auto alloc = [&](size_t bytes) {
    char* q = p;
    p += (bytes + 255) & ~(size_t)255;
    return q;
  };
  int*   counts   = (int*)alloc((size_t)NN * 4);
  int*   rp       = (int*)alloc((size_t)(NN + 1) * 4);
  int*   cursor   = (int*)alloc((size_t)NN * 4);
  int*   bsum     = (int*)alloc(1024 * 4);
  float* inv_deg  = (float*)alloc((size_t)NN * 4);
  int2*  csr_se   = (int2*)alloc((size_t)NE * 8);
  float* t        = (float*)alloc((size_t)NN * 64 * 4);
  float* h        = (float*)alloc((size_t)NN * 64 * 4);
  float* r        = (float*)alloc((size_t)NG * 64 * 4);
  float* y1T      = (float*)alloc((size_t)NG * 512 * 4);
  float* y2T      = (float*)alloc((size_t)NG * 512 * 4);

  hipMemsetAsync(counts, 0, (size_t)NN * 4, stream);
  k_count<<<NE / 256, 256, 0, stream>>>(edge_dst, counts);
  k_scan1<<<NN / 256, 256, 0, stream>>>(counts, rp, bsum);
  k_scan2<<<1, 1024, 0, stream>>>(bsum);
  k_scan3<<<NN / 256, 256, 0, stream>>>(counts, rp, bsum, cursor, inv_deg);
  k_fill<<<NE / 256, 256, 0, stream>>>(edge_src, edge_dst, counts, cursor, csr_se);

  const float* hin = x_mol;
  for (int L = 0; L < 3; L++) {
    k_transform<<<NN / 64, 256, 0, stream>>>(hin, gcn_W + (size_t)L * 64 * 64,
                                             gcn_b + (size_t)L * 64, t);
    k_aggregate<<<NN / 16, 256, 0, stream>>>(t, rp, csr_se, inv_deg, h);
    hin = h;
  }
  k_readout<<<NG / 16, 256, 0, stream>>>(h, graph_ids, r);
  k_dense1<<<NG / 8, 256, 0, stream>>>(r, x_adduct, d1W, d1b, y1T);
  k_dense2<<<256, 256, 0, stream>>>(y1T, d2W, d2b, y2T);
  k_out<<<NG / 256, 256, 0, stream>>>(y2T, oW, obias, out);
}

// Round 11
// 618.862 us; speedup vs baseline: 1.0318x; 1.0318x over previous
//
#include <hip/hip_runtime.h>

#define NN 262144   // nodes
#define NE 1048576  // edges
#define NG 8192     // graphs
#define FD 64       // feature dim
#define AD 8        // adduct dim
#define DN 512      // dense dim

__device__ __forceinline__ int lowerBound(const int* __restrict__ a, int n, int v) {
  int lo = 0, hi = n;
  while (lo < hi) { int mid = (lo + hi) >> 1; if (a[mid] < v) lo = mid + 1; else hi = mid; }
  return lo;
}

// ---------------- CSR build ----------------
__global__ void k_count(const int* __restrict__ dst, int* __restrict__ counts) {
  int e = blockIdx.x * 256 + threadIdx.x;
  if (e < NE) atomicAdd(&counts[dst[e]], 1);
}

__global__ void k_scan1(const int* __restrict__ counts, int* __restrict__ rp,
                        int* __restrict__ bsum) {
  __shared__ int s[256];
  int tid = threadIdx.x;
  int i = blockIdx.x * 256 + tid;
  int orig = counts[i];
  s[tid] = orig;
  __syncthreads();
  for (int off = 1; off < 256; off <<= 1) {
    int v = (tid >= off) ? s[tid - off] : 0;
    __syncthreads();
    s[tid] += v;
    __syncthreads();
  }
  rp[i] = s[tid] - orig;  // block-local exclusive scan
  if (tid == 255) bsum[blockIdx.x] = s[tid];
}

__global__ void k_scan2(int* __restrict__ bsum) {
  __shared__ int s[1024];
  int tid = threadIdx.x;
  int orig = bsum[tid];
  s[tid] = orig;
  __syncthreads();
  for (int off = 1; off < 1024; off <<= 1) {
    int v = (tid >= off) ? s[tid - off] : 0;
    __syncthreads();
    s[tid] += v;
    __syncthreads();
  }
  bsum[tid] = s[tid] - orig;  // exclusive
}

__global__ void k_scan3(const int* __restrict__ counts, int* __restrict__ rp,
                        const int* __restrict__ bsum, int* __restrict__ cursor,
                        float* __restrict__ inv_deg) {
  int i = blockIdx.x * 256 + threadIdx.x;
  int v = rp[i] + bsum[blockIdx.x];
  rp[i] = v;
  cursor[i] = v;
  inv_deg[i] = 1.0f / (float)(counts[i] + 1);
  if (i == 0) rp[NN] = NE;
}

// Packed (src, norm) int2 scatter (validated R10: halves dirty-line traffic).
__global__ void k_fill(const int* __restrict__ src, const int* __restrict__ dst,
                       const int* __restrict__ counts, int* __restrict__ cursor,
                       int2* __restrict__ csr_se) {
  int e = blockIdx.x * 256 + threadIdx.x;
  int s = src[e], d = dst[e];
  float ds = (float)(counts[s] + 1);
  float dd = (float)(counts[d] + 1);
  int pos = atomicAdd(&cursor[d], 1);
  csr_se[pos] = make_int2(s, __float_as_int(rsqrtf(ds * dd)));
}

// ---------------- GCN: t = h @ W + b ----------------
// Classic LDS-tiled GEMM (validated R4: ~28 us/layer, no scratch traffic).
#define HS 68  // hsT row stride (floats): 68*4=272 B, 16B-aligned, breaks pow2 banks
__global__ void __launch_bounds__(256) k_transform(const float* __restrict__ hin,
                                                   const float* __restrict__ W,
                                                   const float* __restrict__ b,
                                                   float* __restrict__ tout) {
  __shared__ float hsT[64 * HS];  // [k][n]  17.4 KB
  __shared__ float Ws[64 * 64];   // [k][c]  16 KB
  int tid = threadIdx.x;
  size_t base = (size_t)blockIdx.x * 64 * 64;

  const float4* h4 = (const float4*)(hin + base);
#pragma unroll
  for (int j = 0; j < 4; j++) {
    int f = tid + 256 * j;        // float4 index within 64x64 tile
    int n = f >> 4, kq = f & 15;  // node row, k-quad
    float4 v = h4[f];
    hsT[(4 * kq + 0) * HS + n] = v.x;
    hsT[(4 * kq + 1) * HS + n] = v.y;
    hsT[(4 * kq + 2) * HS + n] = v.z;
    hsT[(4 * kq + 3) * HS + n] = v.w;
  }
  const float4* w4 = (const float4*)W;
  float4* ws4 = (float4*)Ws;
#pragma unroll
  for (int j = 0; j < 4; j++) ws4[tid + 256 * j] = w4[tid + 256 * j];
  __syncthreads();

  int n0 = (tid >> 4) * 4;  // node quad (16-lane broadcast, free)
  int c0 = (tid & 15) * 4;  // col quad (contiguous 256B, free)
  float acc[4][4];
#pragma unroll
  for (int i = 0; i < 4; i++)
#pragma unroll
    for (int j = 0; j < 4; j++) acc[i][j] = b[c0 + j];

#pragma unroll 4
  for (int k = 0; k < 64; k++) {
    float4 av = *(const float4*)&hsT[k * HS + n0];  // ds_read_b128
    float4 bv = *(const float4*)&Ws[k * 64 + c0];   // ds_read_b128
    acc[0][0] = fmaf(av.x, bv.x, acc[0][0]);
    acc[0][1] = fmaf(av.x, bv.y, acc[0][1]);
    acc[0][2] = fmaf(av.x, bv.z, acc[0][2]);
    acc[0][3] = fmaf(av.x, bv.w, acc[0][3]);
    acc[1][0] = fmaf(av.y, bv.x, acc[1][0]);
    acc[1][1] = fmaf(av.y, bv.y, acc[1][1]);
    acc[1][2] = fmaf(av.y, bv.z, acc[1][2]);
    acc[1][3] = fmaf(av.y, bv.w, acc[1][3]);
    acc[2][0] = fmaf(av.z, bv.x, acc[2][0]);
    acc[2][1] = fmaf(av.z, bv.y, acc[2][1]);
    acc[2][2] = fmaf(av.z, bv.z, acc[2][2]);
    acc[2][3] = fmaf(av.z, bv.w, acc[2][3]);
    acc[3][0] = fmaf(av.w, bv.x, acc[3][0]);
    acc[3][1] = fmaf(av.w, bv.y, acc[3][1]);
    acc[3][2] = fmaf(av.w, bv.z, acc[3][2]);
    acc[3][3] = fmaf(av.w, bv.w, acc[3][3]);
  }

  float4* o4 = (float4*)(tout + base);
#pragma unroll
  for (int i = 0; i < 4; i++) {
    o4[((n0 + i) * 64 + c0) >> 2] =
        make_float4(acc[i][0], acc[i][1], acc[i][2], acc[i][3]);
  }
}

// ---------------- Aggregate: h = relu(sum_{e->n} norm*t[src] + t[n]/deg) ----------------
// 16 lanes per row (float4/lane), 4 nodes/wave, unroll-2 streams, int2 CSR
// (validated R9/R10).
__global__ void k_aggregate(const float* __restrict__ t, const int* __restrict__ rp,
                            const int2* __restrict__ csr_se,
                            const float* __restrict__ inv_deg, float* __restrict__ hout) {
  int tid = threadIdx.x;
  int grp = tid >> 4;   // 16 node-groups per 256-thread block
  int ln  = tid & 15;   // feature quad within row
  int n = blockIdx.x * 16 + grp;
  int beg = rp[n], end = rp[n + 1];
  const float4* t4 = (const float4*)t;

  float4 v = t4[(size_t)n * 16 + ln];
  float sdeg = inv_deg[n];
  float4 a0 = make_float4(v.x * sdeg, v.y * sdeg, v.z * sdeg, v.w * sdeg);
  float4 a1 = make_float4(0.f, 0.f, 0.f, 0.f);

  int idx = beg;
  for (; idx + 2 <= end; idx += 2) {
    int2 e0 = csr_se[idx + 0];
    int2 e1 = csr_se[idx + 1];
    float w0 = __int_as_float(e0.y);
    float w1 = __int_as_float(e1.y);
    float4 v0 = t4[(size_t)e0.x * 16 + ln];
    float4 v1 = t4[(size_t)e1.x * 16 + ln];
    a0.x = fmaf(w0, v0.x, a0.x);
    a0.y = fmaf(w0, v0.y, a0.y);
    a0.z = fmaf(w0, v0.z, a0.z);
    a0.w = fmaf(w0, v0.w, a0.w);
    a1.x = fmaf(w1, v1.x, a1.x);
    a1.y = fmaf(w1, v1.y, a1.y);
    a1.z = fmaf(w1, v1.z, a1.z);
    a1.w = fmaf(w1, v1.w, a1.w);
  }
  if (idx < end) {
    int2 e0 = csr_se[idx];
    float w = __int_as_float(e0.y);
    float4 v0 = t4[(size_t)e0.x * 16 + ln];
    a0.x = fmaf(w, v0.x, a0.x);
    a0.y = fmaf(w, v0.y, a0.y);
    a0.z = fmaf(w, v0.z, a0.z);
    a0.w = fmaf(w, v0.w, a0.w);
  }
  float4 r;
  r.x = fmaxf(a0.x + a1.x, 0.f);
  r.y = fmaxf(a0.y + a1.y, 0.f);
  r.z = fmaxf(a0.z + a1.z, 0.f);
  r.w = fmaxf(a0.w + a1.w, 0.f);
  ((float4*)hout)[(size_t)n * 16 + ln] = r;
}

// ---------------- Readout: graph_ids sorted -> binary-search ranges ----------------
__global__ void k_readout(const float* __restrict__ h, const int* __restrict__ gids,
                          float* __restrict__ r) {
  int tid = threadIdx.x;
  int grp = tid >> 4, ln = tid & 15;
  int g = blockIdx.x * 16 + grp;
  int lo = lowerBound(gids, NN, g);
  int hi = lowerBound(gids, NN, g + 1);
  const float4* h4 = (const float4*)h;
  float4 a0 = make_float4(0.f, 0.f, 0.f, 0.f);
  float4 a1 = make_float4(0.f, 0.f, 0.f, 0.f);
  int n = lo;
  for (; n + 2 <= hi; n += 2) {
    float4 v0 = h4[(size_t)n * 16 + ln];
    float4 v1 = h4[(size_t)(n + 1) * 16 + ln];
    a0.x += v0.x; a0.y += v0.y; a0.z += v0.z; a0.w += v0.w;
    a1.x += v1.x; a1.y += v1.y; a1.z += v1.z; a1.w += v1.w;
  }
  if (n < hi) {
    float4 v0 = h4[(size_t)n * 16 + ln];
    a0.x += v0.x; a0.y += v0.y; a0.z += v0.z; a0.w += v0.w;
  }
  ((float4*)r)[(size_t)g * 16 + ln] =
      make_float4(a0.x + a1.x, a0.y + a1.y, a0.z + a1.z, a0.w + a1.w);
}

// ---------------- Dense head ----------------
// y1T[j][g] = relu(b1[j] + sum_k concat(r,xa)[g][k] * W1[k][j])
// TRANSPOSED output (g-contiguous rows) so dense2/out use lane=graph coalesced.
__global__ void __launch_bounds__(256) k_dense1(const float* __restrict__ r,
                                                const float* __restrict__ xa,
                                                const float* __restrict__ W1,
                                                const float* __restrict__ b1,
                                                float* __restrict__ y1T) {
  __shared__ float xs[8 * 72];
  int tid = threadIdx.x;
  int g0 = blockIdx.x * 8;
  for (int i = tid; i < 8 * 72; i += 256) {
    int g = i / 72, k = i % 72;
    xs[i] = (k < 64) ? r[(size_t)(g0 + g) * 64 + k] : xa[(size_t)(g0 + g) * 8 + (k - 64)];
  }
  __syncthreads();
  float acc[8][2];
#pragma unroll
  for (int g = 0; g < 8; g++) { acc[g][0] = 0.f; acc[g][1] = 0.f; }
  for (int k = 0; k < 72; k++) {
    float w0 = W1[k * 512 + tid];
    float w1 = W1[k * 512 + 256 + tid];
#pragma unroll
    for (int g = 0; g < 8; g++) {
      float xv = xs[g * 72 + k];  // wave-uniform broadcast
      acc[g][0] = fmaf(xv, w0, acc[g][0]);
      acc[g][1] = fmaf(xv, w1, acc[g][1]);
    }
  }
  float bb0 = b1[tid], bb1 = b1[256 + tid];
  float4 v;
  v = make_float4(fmaxf(acc[0][0] + bb0, 0.f), fmaxf(acc[1][0] + bb0, 0.f),
                  fmaxf(acc[2][0] + bb0, 0.f), fmaxf(acc[3][0] + bb0, 0.f));
  *(float4*)&y1T[(size_t)tid * NG + g0] = v;
  v = make_float4(fmaxf(acc[4][0] + bb0, 0.f), fmaxf(acc[5][0] + bb0, 0.f),
                  fmaxf(acc[6][0] + bb0, 0.f), fmaxf(acc[7][0] + bb0, 0.f));
  *(float4*)&y1T[(size_t)tid * NG + g0 + 4] = v;
  v = make_float4(fmaxf(acc[0][1] + bb1, 0.f), fmaxf(acc[1][1] + bb1, 0.f),
                  fmaxf(acc[2][1] + bb1, 0.f), fmaxf(acc[3][1] + bb1, 0.f));
  *(float4*)&y1T[(size_t)(256 + tid) * NG + g0] = v;
  v = make_float4(fmaxf(acc[4][1] + bb1, 0.f), fmaxf(acc[5][1] + bb1, 0.f),
                  fmaxf(acc[6][1] + bb1, 0.f), fmaxf(acc[7][1] + bb1, 0.f));
  *(float4*)&y1T[(size_t)(256 + tid) * NG + g0 + 4] = v;
}

// y2T = relu(W2^T @ xT + b2) as a classic tiled GEMM. R8/R10 post-mortem:
// the old structure was LDS-INSTRUCTION-bound (4.2M ds_read_b128 ~ 8-12 cyc
// each ~ 80 us floor regardless of blocking). Fix: 8x8 register micro-tile ->
// fma:ds_read = 16:1. 128g x 128j tile/block, BK=32, grid 64x4=256.
// Conflict-free LDS: g-reads 4*(tid&15) (16 contiguous float4, free);
// j-reads 4*(tid>>4) (4 distinct, 16-lane broadcast, free); micro-tile
// indices {q, 64+q} dodge the stride-32B 4-way conflict.
// Per-CU per-k: LDS 16 reads x 8 cyc = 128 cyc vs VALU 128 cyc/SIMD ->
// balanced at the 27 us VALU floor.
#define DBK 32
__global__ void __launch_bounds__(256) k_dense2(const float* __restrict__ xT,
                                                const float* __restrict__ W2,
                                                const float* __restrict__ b2,
                                                float* __restrict__ y2T) {
  __shared__ float xs[DBK * 128];  // [k][g] 16 KB
  __shared__ float ws[DBK * 128];  // [k][j] 16 KB
  int tid = threadIdx.x;
  int g0 = (blockIdx.x & 63) * 128;
  int j0 = (blockIdx.x >> 6) * 128;
  int ga = (tid & 15) * 4;   // thread g-offsets: {ga..ga+3, 64+ga..64+ga+3}
  int jb = (tid >> 4) * 4;   // thread j-offsets: {jb..jb+3, 64+jb..64+jb+3}

  float acc[8][8];  // [j][g]
#pragma unroll
  for (int jh = 0; jh < 2; jh++)
#pragma unroll
    for (int jl = 0; jl < 4; jl++) {
      float bb = b2[j0 + jh * 64 + jb + jl];
#pragma unroll
      for (int gg = 0; gg < 8; gg++) acc[jh * 4 + jl][gg] = bb;
    }

  for (int kb = 0; kb < 512; kb += DBK) {
    __syncthreads();
    // stage x-tile [32k][128g] and W-tile [32k][128j]; 4 float4 each/thread
#pragma unroll
    for (int i = 0; i < 4; i++) {
      int f = tid + 256 * i;
      int kr = f >> 5, gc = f & 31;
      ((float4*)xs)[f] = ((const float4*)(xT + (size_t)(kb + kr) * NG + g0))[gc];
      ((float4*)ws)[f] = ((const float4*)(W2 + (size_t)(kb + kr) * 512 + j0))[gc];
    }
    __syncthreads();
#pragma unroll 4
    for (int k = 0; k < DBK; k++) {
      float4 x0 = *(const float4*)&xs[k * 128 + ga];
      float4 x1 = *(const float4*)&xs[k * 128 + 64 + ga];
      float4 w0 = *(const float4*)&ws[k * 128 + jb];
      float4 w1 = *(const float4*)&ws[k * 128 + 64 + jb];
      float xv[8] = {x0.x, x0.y, x0.z, x0.w, x1.x, x1.y, x1.z, x1.w};
      float wv[8] = {w0.x, w0.y, w0.z, w0.w, w1.x, w1.y, w1.z, w1.w};
#pragma unroll
      for (int jj = 0; jj < 8; jj++)
#pragma unroll
        for (int gg = 0; gg < 8; gg++)
          acc[jj][gg] = fmaf(wv[jj], xv[gg], acc[jj][gg]);
    }
  }

#pragma unroll
  for (int jh = 0; jh < 2; jh++)
#pragma unroll
    for (int jl = 0; jl < 4; jl++) {
      int j = j0 + jh * 64 + jb + jl;
      float* row = y2T + (size_t)j * NG + g0;
      const float* a = acc[jh * 4 + jl];
      *(float4*)&row[ga] =
          make_float4(fmaxf(a[0], 0.f), fmaxf(a[1], 0.f), fmaxf(a[2], 0.f), fmaxf(a[3], 0.f));
      *(float4*)&row[64 + ga] =
          make_float4(fmaxf(a[4], 0.f), fmaxf(a[5], 0.f), fmaxf(a[6], 0.f), fmaxf(a[7], 0.f));
    }
}

// out[g] = y2T[:,g] . out_W + out_b  -- lane = graph, coalesced, no shuffle
__global__ void k_out(const float* __restrict__ y2T, const float* __restrict__ ow,
                      const float* __restrict__ ob, float* __restrict__ out) {
  int g = blockIdx.x * 256 + threadIdx.x;
  float s0 = 0.f, s1 = 0.f, s2 = 0.f, s3 = 0.f;
#pragma unroll 4
  for (int j = 0; j < 512; j += 4) {
    s0 = fmaf(y2T[(size_t)(j + 0) * NG + g], ow[j + 0], s0);
    s1 = fmaf(y2T[(size_t)(j + 1) * NG + g], ow[j + 1], s1);
    s2 = fmaf(y2T[(size_t)(j + 2) * NG + g], ow[j + 2], s2);
    s3 = fmaf(y2T[(size_t)(j + 3) * NG + g], ow[j + 3], s3);
  }
  out[g] = (s0 + s1) + (s2 + s3) + ob[0];
}

extern "C" void kernel_launch(void* const* d_in, const int* in_sizes, int n_in,
                              void* d_out, int out_size, void* d_ws, size_t ws_size,
                              hipStream_t stream) {
  const float* x_mol    = (const float*)d_in[0];
  const float* x_adduct = (const float*)d_in[1];
  const int*   edge_src = (const int*)d_in[2];
  const int*   edge_dst = (const int*)d_in[3];
  const int*   graph_ids= (const int*)d_in[4];
  const float* gcn_W    = (const float*)d_in[5];
  const float* gcn_b    = (const float*)d_in[6];
  const float* d1W      = (const float*)d_in[7];
  const float* d1b      = (const float*)d_in[8];
  const float* d2W      = (const float*)d_in[9];
  const float* d2b      = (const float*)d_in[10];
  const float* oW       = (const float*)d_in[11];
  const float* obias    = (const float*)d_in[12];
  float* out = (float*)d_out;

  char* p = (char*)d_ws;
  auto alloc = [&](size_t bytes) {
    char* q = p;
    p += (bytes + 255) & ~(size_t)255;
    return q;
  };
  int*   counts   = (int*)alloc((size_t)NN * 4);
  int*   rp       = (int*)alloc((size_t)(NN + 1) * 4);
  int*   cursor   = (int*)alloc((size_t)NN * 4);
  int*   bsum     = (int*)alloc(1024 * 4);
  float* inv_deg  = (float*)alloc((size_t)NN * 4);
  int2*  csr_se   = (int2*)alloc((size_t)NE * 8);
  float* t        = (float*)alloc((size_t)NN * 64 * 4);
  float* h        = (float*)alloc((size_t)NN * 64 * 4);
  float* r        = (float*)alloc((size_t)NG * 64 * 4);
  float* y1T      = (float*)alloc((size_t)NG * 512 * 4);
  float* y2T      = (float*)alloc((size_t)NG * 512 * 4);

  hipMemsetAsync(counts, 0, (size_t)NN * 4, stream);
  k_count<<<NE / 256, 256, 0, stream>>>(edge_dst, counts);
  k_scan1<<<NN / 256, 256, 0, stream>>>(counts, rp, bsum);
  k_scan2<<<1, 1024, 0, stream>>>(bsum);
  k_scan3<<<NN / 256, 256, 0, stream>>>(counts, rp, bsum, cursor, inv_deg);
  k_fill<<<NE / 256, 256, 0, stream>>>(edge_src, edge_dst, counts, cursor, csr_se);

  const float* hin = x_mol;
  for (int L = 0; L < 3; L++) {
    k_transform<<<NN / 64, 256, 0, stream>>>(hin, gcn_W + (size_t)L * 64 * 64,
                                             gcn_b + (size_t)L * 64, t);
    k_aggregate<<<NN / 16, 256, 0, stream>>>(t, rp, csr_se, inv_deg, h);
    hin = h;
  }
  k_readout<<<NG / 16, 256, 0, stream>>>(h, graph_ids, r);
  k_dense1<<<NG / 8, 256, 0, stream>>>(r, x_adduct, d1W, d1b, y1T);
  k_dense2<<<256, 256, 0, stream>>>(y1T, d2W, d2b, y2T);
  k_out<<<NG / 256, 256, 0, stream>>>(y2T, oW, obias, out);
}

// Round 12
// 597.023 us; speedup vs baseline: 1.0696x; 1.0366x over previous
//
#include <hip/hip_runtime.h>

#define NN 262144   // nodes
#define NE 1048576  // edges
#define NG 8192     // graphs
#define FD 64       // feature dim
#define AD 8        // adduct dim
#define DN 512      // dense dim

__device__ __forceinline__ int lowerBound(const int* __restrict__ a, int n, int v) {
  int lo = 0, hi = n;
  while (lo < hi) { int mid = (lo + hi) >> 1; if (a[mid] < v) lo = mid + 1; else hi = mid; }
  return lo;
}

// ---------------- CSR build ----------------
__global__ void k_count(const int* __restrict__ dst, int* __restrict__ counts) {
  int e = blockIdx.x * 256 + threadIdx.x;
  if (e < NE) atomicAdd(&counts[dst[e]], 1);
}

__global__ void k_scan1(const int* __restrict__ counts, int* __restrict__ rp,
                        int* __restrict__ bsum) {
  __shared__ int s[256];
  int tid = threadIdx.x;
  int i = blockIdx.x * 256 + tid;
  int orig = counts[i];
  s[tid] = orig;
  __syncthreads();
  for (int off = 1; off < 256; off <<= 1) {
    int v = (tid >= off) ? s[tid - off] : 0;
    __syncthreads();
    s[tid] += v;
    __syncthreads();
  }
  rp[i] = s[tid] - orig;  // block-local exclusive scan
  if (tid == 255) bsum[blockIdx.x] = s[tid];
}

__global__ void k_scan2(int* __restrict__ bsum) {
  __shared__ int s[1024];
  int tid = threadIdx.x;
  int orig = bsum[tid];
  s[tid] = orig;
  __syncthreads();
  for (int off = 1; off < 1024; off <<= 1) {
    int v = (tid >= off) ? s[tid - off] : 0;
    __syncthreads();
    s[tid] += v;
    __syncthreads();
  }
  bsum[tid] = s[tid] - orig;  // exclusive
}

__global__ void k_scan3(const int* __restrict__ counts, int* __restrict__ rp,
                        const int* __restrict__ bsum, int* __restrict__ cursor,
                        float* __restrict__ inv_deg) {
  int i = blockIdx.x * 256 + threadIdx.x;
  int v = rp[i] + bsum[blockIdx.x];
  rp[i] = v;
  cursor[i] = v;
  inv_deg[i] = 1.0f / (float)(counts[i] + 1);
  if (i == 0) rp[NN] = NE;
}

// Packed (src, norm) int2 scatter (validated R10). R12: 2 edges/thread ->
// two independent atomic->store chains in flight.
__global__ void k_fill(const int* __restrict__ src, const int* __restrict__ dst,
                       const int* __restrict__ counts, int* __restrict__ cursor,
                       int2* __restrict__ csr_se) {
  int e0 = blockIdx.x * 512 + threadIdx.x;
  int e1 = e0 + 256;
  int s0 = src[e0], d0 = dst[e0];
  int s1 = src[e1], d1 = dst[e1];
  float n0 = rsqrtf((float)(counts[s0] + 1) * (float)(counts[d0] + 1));
  float n1 = rsqrtf((float)(counts[s1] + 1) * (float)(counts[d1] + 1));
  int p0 = atomicAdd(&cursor[d0], 1);
  int p1 = atomicAdd(&cursor[d1], 1);
  csr_se[p0] = make_int2(s0, __float_as_int(n0));
  csr_se[p1] = make_int2(s1, __float_as_int(n1));
}

// ---------------- GCN: t = h @ W + b ----------------
// Classic LDS-tiled GEMM (validated R4: ~28 us/layer, no scratch traffic).
#define HS 68  // hsT row stride (floats): 68*4=272 B, 16B-aligned, breaks pow2 banks
__global__ void __launch_bounds__(256) k_transform(const float* __restrict__ hin,
                                                   const float* __restrict__ W,
                                                   const float* __restrict__ b,
                                                   float* __restrict__ tout) {
  __shared__ float hsT[64 * HS];  // [k][n]  17.4 KB
  __shared__ float Ws[64 * 64];   // [k][c]  16 KB
  int tid = threadIdx.x;
  size_t base = (size_t)blockIdx.x * 64 * 64;

  const float4* h4 = (const float4*)(hin + base);
#pragma unroll
  for (int j = 0; j < 4; j++) {
    int f = tid + 256 * j;        // float4 index within 64x64 tile
    int n = f >> 4, kq = f & 15;  // node row, k-quad
    float4 v = h4[f];
    hsT[(4 * kq + 0) * HS + n] = v.x;
    hsT[(4 * kq + 1) * HS + n] = v.y;
    hsT[(4 * kq + 2) * HS + n] = v.z;
    hsT[(4 * kq + 3) * HS + n] = v.w;
  }
  const float4* w4 = (const float4*)W;
  float4* ws4 = (float4*)Ws;
#pragma unroll
  for (int j = 0; j < 4; j++) ws4[tid + 256 * j] = w4[tid + 256 * j];
  __syncthreads();

  int n0 = (tid >> 4) * 4;  // node quad (16-lane broadcast, free)
  int c0 = (tid & 15) * 4;  // col quad (contiguous 256B, free)
  float acc[4][4];
#pragma unroll
  for (int i = 0; i < 4; i++)
#pragma unroll
    for (int j = 0; j < 4; j++) acc[i][j] = b[c0 + j];

#pragma unroll 4
  for (int k = 0; k < 64; k++) {
    float4 av = *(const float4*)&hsT[k * HS + n0];  // ds_read_b128
    float4 bv = *(const float4*)&Ws[k * 64 + c0];   // ds_read_b128
    acc[0][0] = fmaf(av.x, bv.x, acc[0][0]);
    acc[0][1] = fmaf(av.x, bv.y, acc[0][1]);
    acc[0][2] = fmaf(av.x, bv.z, acc[0][2]);
    acc[0][3] = fmaf(av.x, bv.w, acc[0][3]);
    acc[1][0] = fmaf(av.y, bv.x, acc[1][0]);
    acc[1][1] = fmaf(av.y, bv.y, acc[1][1]);
    acc[1][2] = fmaf(av.y, bv.z, acc[1][2]);
    acc[1][3] = fmaf(av.y, bv.w, acc[1][3]);
    acc[2][0] = fmaf(av.z, bv.x, acc[2][0]);
    acc[2][1] = fmaf(av.z, bv.y, acc[2][1]);
    acc[2][2] = fmaf(av.z, bv.z, acc[2][2]);
    acc[2][3] = fmaf(av.z, bv.w, acc[2][3]);
    acc[3][0] = fmaf(av.w, bv.x, acc[3][0]);
    acc[3][1] = fmaf(av.w, bv.y, acc[3][1]);
    acc[3][2] = fmaf(av.w, bv.z, acc[3][2]);
    acc[3][3] = fmaf(av.w, bv.w, acc[3][3]);
  }

  float4* o4 = (float4*)(tout + base);
#pragma unroll
  for (int i = 0; i < 4; i++) {
    o4[((n0 + i) * 64 + c0) >> 2] =
        make_float4(acc[i][0], acc[i][1], acc[i][2], acc[i][3]);
  }
}

// ---------------- Aggregate: h = relu(sum_{e->n} norm*t[src] + t[n]/deg) ----------------
// 16 lanes per row (float4/lane), 4 nodes/wave, int2 CSR. R12: unroll-4
// independent streams -> up to 16 rows in flight per wave.
__global__ void k_aggregate(const float* __restrict__ t, const int* __restrict__ rp,
                            const int2* __restrict__ csr_se,
                            const float* __restrict__ inv_deg, float* __restrict__ hout) {
  int tid = threadIdx.x;
  int grp = tid >> 4;   // 16 node-groups per 256-thread block
  int ln  = tid & 15;   // feature quad within row
  int n = blockIdx.x * 16 + grp;
  int beg = rp[n], end = rp[n + 1];
  const float4* t4 = (const float4*)t;

  float4 v = t4[(size_t)n * 16 + ln];
  float sdeg = inv_deg[n];
  float4 a0 = make_float4(v.x * sdeg, v.y * sdeg, v.z * sdeg, v.w * sdeg);
  float4 a1 = make_float4(0.f, 0.f, 0.f, 0.f);
  float4 a2 = make_float4(0.f, 0.f, 0.f, 0.f);
  float4 a3 = make_float4(0.f, 0.f, 0.f, 0.f);

  int idx = beg;
  for (; idx + 4 <= end; idx += 4) {
    int2 e0 = csr_se[idx + 0];
    int2 e1 = csr_se[idx + 1];
    int2 e2 = csr_se[idx + 2];
    int2 e3 = csr_se[idx + 3];
    float4 v0 = t4[(size_t)e0.x * 16 + ln];
    float4 v1 = t4[(size_t)e1.x * 16 + ln];
    float4 v2 = t4[(size_t)e2.x * 16 + ln];
    float4 v3 = t4[(size_t)e3.x * 16 + ln];
    float w0 = __int_as_float(e0.y);
    float w1 = __int_as_float(e1.y);
    float w2 = __int_as_float(e2.y);
    float w3 = __int_as_float(e3.y);
    a0.x = fmaf(w0, v0.x, a0.x); a0.y = fmaf(w0, v0.y, a0.y);
    a0.z = fmaf(w0, v0.z, a0.z); a0.w = fmaf(w0, v0.w, a0.w);
    a1.x = fmaf(w1, v1.x, a1.x); a1.y = fmaf(w1, v1.y, a1.y);
    a1.z = fmaf(w1, v1.z, a1.z); a1.w = fmaf(w1, v1.w, a1.w);
    a2.x = fmaf(w2, v2.x, a2.x); a2.y = fmaf(w2, v2.y, a2.y);
    a2.z = fmaf(w2, v2.z, a2.z); a2.w = fmaf(w2, v2.w, a2.w);
    a3.x = fmaf(w3, v3.x, a3.x); a3.y = fmaf(w3, v3.y, a3.y);
    a3.z = fmaf(w3, v3.z, a3.z); a3.w = fmaf(w3, v3.w, a3.w);
  }
  if (idx + 2 <= end) {
    int2 e0 = csr_se[idx + 0];
    int2 e1 = csr_se[idx + 1];
    float4 v0 = t4[(size_t)e0.x * 16 + ln];
    float4 v1 = t4[(size_t)e1.x * 16 + ln];
    float w0 = __int_as_float(e0.y);
    float w1 = __int_as_float(e1.y);
    a0.x = fmaf(w0, v0.x, a0.x); a0.y = fmaf(w0, v0.y, a0.y);
    a0.z = fmaf(w0, v0.z, a0.z); a0.w = fmaf(w0, v0.w, a0.w);
    a1.x = fmaf(w1, v1.x, a1.x); a1.y = fmaf(w1, v1.y, a1.y);
    a1.z = fmaf(w1, v1.z, a1.z); a1.w = fmaf(w1, v1.w, a1.w);
    idx += 2;
  }
  if (idx < end) {
    int2 e0 = csr_se[idx];
    float w = __int_as_float(e0.y);
    float4 v0 = t4[(size_t)e0.x * 16 + ln];
    a0.x = fmaf(w, v0.x, a0.x); a0.y = fmaf(w, v0.y, a0.y);
    a0.z = fmaf(w, v0.z, a0.z); a0.w = fmaf(w, v0.w, a0.w);
  }
  float4 r;
  r.x = fmaxf((a0.x + a1.x) + (a2.x + a3.x), 0.f);
  r.y = fmaxf((a0.y + a1.y) + (a2.y + a3.y), 0.f);
  r.z = fmaxf((a0.z + a1.z) + (a2.z + a3.z), 0.f);
  r.w = fmaxf((a0.w + a1.w) + (a2.w + a3.w), 0.f);
  ((float4*)hout)[(size_t)n * 16 + ln] = r;
}

// ---------------- Readout: graph_ids sorted -> binary-search ranges ----------------
__global__ void k_readout(const float* __restrict__ h, const int* __restrict__ gids,
                          float* __restrict__ r) {
  int tid = threadIdx.x;
  int grp = tid >> 4, ln = tid & 15;
  int g = blockIdx.x * 16 + grp;
  int lo = lowerBound(gids, NN, g);
  int hi = lowerBound(gids, NN, g + 1);
  const float4* h4 = (const float4*)h;
  float4 a0 = make_float4(0.f, 0.f, 0.f, 0.f);
  float4 a1 = make_float4(0.f, 0.f, 0.f, 0.f);
  int n = lo;
  for (; n + 2 <= hi; n += 2) {
    float4 v0 = h4[(size_t)n * 16 + ln];
    float4 v1 = h4[(size_t)(n + 1) * 16 + ln];
    a0.x += v0.x; a0.y += v0.y; a0.z += v0.z; a0.w += v0.w;
    a1.x += v1.x; a1.y += v1.y; a1.z += v1.z; a1.w += v1.w;
  }
  if (n < hi) {
    float4 v0 = h4[(size_t)n * 16 + ln];
    a0.x += v0.x; a0.y += v0.y; a0.z += v0.z; a0.w += v0.w;
  }
  ((float4*)r)[(size_t)g * 16 + ln] =
      make_float4(a0.x + a1.x, a0.y + a1.y, a0.z + a1.z, a0.w + a1.w);
}

// ---------------- Dense head ----------------
// y1T[j][g] = relu(b1[j] + sum_k concat(r,xa)[g][k] * W1[k][j])
// TRANSPOSED output (g-contiguous rows) so dense2/out use lane=graph coalesced.
__global__ void __launch_bounds__(256) k_dense1(const float* __restrict__ r,
                                                const float* __restrict__ xa,
                                                const float* __restrict__ W1,
                                                const float* __restrict__ b1,
                                                float* __restrict__ y1T) {
  __shared__ float xs[8 * 72];
  int tid = threadIdx.x;
  int g0 = blockIdx.x * 8;
  for (int i = tid; i < 8 * 72; i += 256) {
    int g = i / 72, k = i % 72;
    xs[i] = (k < 64) ? r[(size_t)(g0 + g) * 64 + k] : xa[(size_t)(g0 + g) * 8 + (k - 64)];
  }
  __syncthreads();
  float acc[8][2];
#pragma unroll
  for (int g = 0; g < 8; g++) { acc[g][0] = 0.f; acc[g][1] = 0.f; }
  for (int k = 0; k < 72; k++) {
    float w0 = W1[k * 512 + tid];
    float w1 = W1[k * 512 + 256 + tid];
#pragma unroll
    for (int g = 0; g < 8; g++) {
      float xv = xs[g * 72 + k];  // wave-uniform broadcast
      acc[g][0] = fmaf(xv, w0, acc[g][0]);
      acc[g][1] = fmaf(xv, w1, acc[g][1]);
    }
  }
  float bb0 = b1[tid], bb1 = b1[256 + tid];
  float4 v;
  v = make_float4(fmaxf(acc[0][0] + bb0, 0.f), fmaxf(acc[1][0] + bb0, 0.f),
                  fmaxf(acc[2][0] + bb0, 0.f), fmaxf(acc[3][0] + bb0, 0.f));
  *(float4*)&y1T[(size_t)tid * NG + g0] = v;
  v = make_float4(fmaxf(acc[4][0] + bb0, 0.f), fmaxf(acc[5][0] + bb0, 0.f),
                  fmaxf(acc[6][0] + bb0, 0.f), fmaxf(acc[7][0] + bb0, 0.f));
  *(float4*)&y1T[(size_t)tid * NG + g0 + 4] = v;
  v = make_float4(fmaxf(acc[0][1] + bb1, 0.f), fmaxf(acc[1][1] + bb1, 0.f),
                  fmaxf(acc[2][1] + bb1, 0.f), fmaxf(acc[3][1] + bb1, 0.f));
  *(float4*)&y1T[(size_t)(256 + tid) * NG + g0] = v;
  v = make_float4(fmaxf(acc[4][1] + bb1, 0.f), fmaxf(acc[5][1] + bb1, 0.f),
                  fmaxf(acc[6][1] + bb1, 0.f), fmaxf(acc[7][1] + bb1, 0.f));
  *(float4*)&y1T[(size_t)(256 + tid) * NG + g0 + 4] = v;
}

// y2T = relu(W2^T @ xT + b2), tiled GEMM. R11 post-mortem: 8x8 micro-tile =
// 64 outputs/thread = only 1024 waves device-wide = 1 wave/SIMD -> latency-
// exposed (occupancy 10%, VALUBusy 36%). R12: 512 threads/block, 8g x 4j
// micro-tile (32/thread) -> 8 waves/block, 2 waves/SIMD. Per k: 3
// ds_read_b128 + 32 fma. LDS floor ~41 us but now latency-hidden.
#define DBK 32
__global__ void __launch_bounds__(512) k_dense2(const float* __restrict__ xT,
                                                const float* __restrict__ W2,
                                                const float* __restrict__ b2,
                                                float* __restrict__ y2T) {
  __shared__ float xs[DBK * 128];  // [k][g] 16 KB
  __shared__ float ws[DBK * 128];  // [k][j] 16 KB
  int tid = threadIdx.x;  // 512
  int g0 = (blockIdx.x & 63) * 128;
  int j0 = (blockIdx.x >> 6) * 128;
  int ga = (tid & 15) * 4;         // g offsets {ga..ga+3, 64+ga..64+ga+3}
  int jb = (tid >> 4) * 4;         // j offsets {jb..jb+3}  (32 quads cover 128)

  float acc[4][8];  // [j][g]
#pragma unroll
  for (int jl = 0; jl < 4; jl++) {
    float bb = b2[j0 + jb + jl];
#pragma unroll
    for (int gg = 0; gg < 8; gg++) acc[jl][gg] = bb;
  }

  for (int kb = 0; kb < 512; kb += DBK) {
    __syncthreads();
    // stage x-tile [32k][128g] and W-tile [32k][128j]; 1024 float4 each,
    // 2 per thread per array
#pragma unroll
    for (int i = 0; i < 2; i++) {
      int f = tid + 512 * i;
      int kr = f >> 5, gc = f & 31;
      ((float4*)xs)[f] = ((const float4*)(xT + (size_t)(kb + kr) * NG + g0))[gc];
      ((float4*)ws)[f] = ((const float4*)(W2 + (size_t)(kb + kr) * 512 + j0))[gc];
    }
    __syncthreads();
#pragma unroll 4
    for (int k = 0; k < DBK; k++) {
      float4 x0 = *(const float4*)&xs[k * 128 + ga];       // 16 contiguous f4/16 lanes
      float4 x1 = *(const float4*)&xs[k * 128 + 64 + ga];
      float4 w0 = *(const float4*)&ws[k * 128 + jb];       // 4 distinct -> broadcast
      float xv[8] = {x0.x, x0.y, x0.z, x0.w, x1.x, x1.y, x1.z, x1.w};
      float wv[4] = {w0.x, w0.y, w0.z, w0.w};
#pragma unroll
      for (int jj = 0; jj < 4; jj++)
#pragma unroll
        for (int gg = 0; gg < 8; gg++)
          acc[jj][gg] = fmaf(wv[jj], xv[gg], acc[jj][gg]);
    }
  }

#pragma unroll
  for (int jl = 0; jl < 4; jl++) {
    int j = j0 + jb + jl;
    float* row = y2T + (size_t)j * NG + g0;
    const float* a = acc[jl];
    *(float4*)&row[ga] =
        make_float4(fmaxf(a[0], 0.f), fmaxf(a[1], 0.f), fmaxf(a[2], 0.f), fmaxf(a[3], 0.f));
    *(float4*)&row[64 + ga] =
        make_float4(fmaxf(a[4], 0.f), fmaxf(a[5], 0.f), fmaxf(a[6], 0.f), fmaxf(a[7], 0.f));
  }
}

// out[g] = y2T[:,g] . out_W + out_b  -- lane = graph, coalesced, no shuffle
__global__ void k_out(const float* __restrict__ y2T, const float* __restrict__ ow,
                      const float* __restrict__ ob, float* __restrict__ out) {
  int g = blockIdx.x * 256 + threadIdx.x;
  float s0 = 0.f, s1 = 0.f, s2 = 0.f, s3 = 0.f;
#pragma unroll 4
  for (int j = 0; j < 512; j += 4) {
    s0 = fmaf(y2T[(size_t)(j + 0) * NG + g], ow[j + 0], s0);
    s1 = fmaf(y2T[(size_t)(j + 1) * NG + g], ow[j + 1], s1);
    s2 = fmaf(y2T[(size_t)(j + 2) * NG + g], ow[j + 2], s2);
    s3 = fmaf(y2T[(size_t)(j + 3) * NG + g], ow[j + 3], s3);
  }
  out[g] = (s0 + s1) + (s2 + s3) + ob[0];
}

extern "C" void kernel_launch(void* const* d_in, const int* in_sizes, int n_in,
                              void* d_out, int out_size, void* d_ws, size_t ws_size,
                              hipStream_t stream) {
  const float* x_mol    = (const float*)d_in[0];
  const float* x_adduct = (const float*)d_in[1];
  const int*   edge_src = (const int*)d_in[2];
  const int*   edge_dst = (const int*)d_in[3];
  const int*   graph_ids= (const int*)d_in[4];
  const float* gcn_W    = (const float*)d_in[5];
  const float* gcn_b    = (const float*)d_in[6];
  const float* d1W      = (const float*)d_in[7];
  const float* d1b      = (const float*)d_in[8];
  const float* d2W      = (const float*)d_in[9];
  const float* d2b      = (const float*)d_in[10];
  const float* oW       = (const float*)d_in[11];
  const float* obias    = (const float*)d_in[12];
  float* out = (float*)d_out;

  char* p = (char*)d_ws;
  auto alloc = [&](size_t bytes) {
    char* q = p;
    p += (bytes + 255) & ~(size_t)255;
    return q;
  };
  int*   counts   = (int*)alloc((size_t)NN * 4);
  int*   rp       = (int*)alloc((size_t)(NN + 1) * 4);
  int*   cursor   = (int*)alloc((size_t)NN * 4);
  int*   bsum     = (int*)alloc(1024 * 4);
  float* inv_deg  = (float*)alloc((size_t)NN * 4);
  int2*  csr_se   = (int2*)alloc((size_t)NE * 8);
  float* t        = (float*)alloc((size_t)NN * 64 * 4);
  float* h        = (float*)alloc((size_t)NN * 64 * 4);
  float* r        = (float*)alloc((size_t)NG * 64 * 4);
  float* y1T      = (float*)alloc((size_t)NG * 512 * 4);
  float* y2T      = (float*)alloc((size_t)NG * 512 * 4);

  hipMemsetAsync(counts, 0, (size_t)NN * 4, stream);
  k_count<<<NE / 256, 256, 0, stream>>>(edge_dst, counts);
  k_scan1<<<NN / 256, 256, 0, stream>>>(counts, rp, bsum);
  k_scan2<<<1, 1024, 0, stream>>>(bsum);
  k_scan3<<<NN / 256, 256, 0, stream>>>(counts, rp, bsum, cursor, inv_deg);
  k_fill<<<NE / 512, 256, 0, stream>>>(edge_src, edge_dst, counts, cursor, csr_se);

  const float* hin = x_mol;
  for (int L = 0; L < 3; L++) {
    k_transform<<<NN / 64, 256, 0, stream>>>(hin, gcn_W + (size_t)L * 64 * 64,
                                             gcn_b + (size_t)L * 64, t);
    k_aggregate<<<NN / 16, 256, 0, stream>>>(t, rp, csr_se, inv_deg, h);
    hin = h;
  }
  k_readout<<<NG / 16, 256, 0, stream>>>(h, graph_ids, r);
  k_dense1<<<NG / 8, 256, 0, stream>>>(r, x_adduct, d1W, d1b, y1T);
  k_dense2<<<256, 512, 0, stream>>>(y1T, d2W, d2b, y2T);
  k_out<<<NG / 256, 256, 0, stream>>>(y2T, oW, obias, out);
}